// Round 19
// baseline (61.817 us; speedup 1.0000x reference)
//
#include <hip/hip_runtime.h>

#define LSEQ 2048
#define DIN  1330
#define NB   8
#define SPLITK 2
#define KCH 768          // floats per k-chunk; 2*768 = 1536 (zero-padded)
#define K1PAD 1536

typedef short bf16x8 __attribute__((ext_vector_type(8)));
typedef float f32x4  __attribute__((ext_vector_type(4)));

__device__ __forceinline__ float lsef(float a, float b) {
  float m = fmaxf(a, b);
  float d = fminf(a, b) - m;
  return m + log1pf(__expf(d));
}

__device__ __forceinline__ unsigned short f2bf(float f) {   // RNE
  unsigned int u = __float_as_uint(f);
  return (unsigned short)((u + 0x7FFFu + ((u >> 16) & 1u)) >> 16);
}

// async global->LDS, 16B per lane: dest = uniform base + lane*16, src per-lane.
#define GLDS(g, l) __builtin_amdgcn_global_load_lds( \
    (const __attribute__((address_space(1))) void*)(g), \
    (__attribute__((address_space(3))) void*)(l), 16, 0, 0)

// ---------------- K0: w1 fp32 [k][h] -> w1T bf16 [h][K1PAD] (zero-padded) --------
__global__ __launch_bounds__(256) void k0_wt(
    const float* __restrict__ w1, unsigned short* __restrict__ w1T) {
  const int f = (blockIdx.x * 256 + threadIdx.x) * 4;   // 48 blocks * 1024 = 49152
  const int h = f / K1PAD, k = f % K1PAD;               // 1536 % 4 == 0
  ushort4 v;
  v.x = (k     < DIN) ? f2bf(w1[(long)(k)     * 32 + h]) : (unsigned short)0;
  v.y = (k + 1 < DIN) ? f2bf(w1[(long)(k + 1) * 32 + h]) : (unsigned short)0;
  v.z = (k + 2 < DIN) ? f2bf(w1[(long)(k + 2) * 32 + h]) : (unsigned short)0;
  v.w = (k + 3 < DIN) ? f2bf(w1[(long)(k + 3) * 32 + h]) : (unsigned short)0;
  *(ushort4*)(w1T + f) = v;
}

// ---------------- K1: p[s] = x[:,ks] @ w1[ks,:] via MFMA + global_load_lds --------
// v16: every prior design (r10-r18, 41-67us) staged x via VGPR loads; in-flight
// bytes/CU ~2-4KB -> Little's-law cap ~2 TB/s, invariant to occupancy/barriers.
// global_load_lds gives HW queue depth without VGPR: per row 3x1KB contiguous
// wave-issues; 12KB in flight/wave x 12 waves/CU = saturated. x stays fp32 in
// LDS (49KB, 3 blocks/CU); bf16 convert at frag read. 16 rows x 768 k per block;
// 4 waves = 2 h-halves x 2 k-quarters + LDS scratch reduce. OOB tail (row 16383,
// s=1): manual guarded stage for that one row.
__global__ __launch_bounds__(256) void k1_mfma(
    const float* __restrict__ x, const unsigned short* __restrict__ w1T,
    float* __restrict__ p) {
  __shared__ float sA[16 * KCH];          // 49152 B, linear [row][k]
  __shared__ float sc[2][16][16];         // reduce scratch, 2 KB

  const int tid = threadIdx.x;
  const int rb  = blockIdx.x >> 1;        // 0..1023
  const int s   = blockIdx.x & 1;
  const int k0  = s * KCH;
  const long row0 = (long)rb * 16;

  const int wv   = tid >> 6;
  const int lane = tid & 63;
  const int fr   = lane & 15;
  const int fg   = lane >> 4;

  // ---- stage 16 rows x 768 floats (fp32) ----
  const bool special = (blockIdx.x == 2047);   // rb=1023, s=1: row 16383 OOB tail
  #pragma unroll
  for (int j = 0; j < 4; ++j) {
    const int r = wv * 4 + j;
    const long grow = row0 + r;
    if (special && r == 15) {
      for (int c = lane; c < KCH; c += 64) {
        const int kg = k0 + c;
        sA[r * KCH + c] = (kg < DIN) ? x[grow * DIN + kg] : 0.f;
      }
    } else {
      const float* gsrc = x + grow * DIN + k0 + lane * 4;
      float* ldst = &sA[r * KCH];
      GLDS(gsrc,       ldst);        // floats [  0,256) of window
      GLDS(gsrc + 256, ldst + 256);  // floats [256,512)
      GLDS(gsrc + 512, ldst + 512);  // floats [512,768)
    }
  }
  __syncthreads();   // compiler drains vmcnt for global_load_lds

  // ---- compute: wave = (h-half hh, k-quarter kq), 12 MFMA steps ----
  const int hh = wv & 1;
  const int kq = wv >> 1;
  const unsigned short* bp = w1T + (long)(hh * 16 + fr) * K1PAD + k0;

  f32x4 acc = {0.f, 0.f, 0.f, 0.f};
  #pragma unroll 4
  for (int t = kq * 12; t < kq * 12 + 12; ++t) {
    const int fi = t * 32 + fg * 8;
    const float* pa = sA + fr * KCH + fi;
    const float4 u = *(const float4*)(pa);
    const float4 v = *(const float4*)(pa + 4);
    bf16x8 a;
    a[0] = (short)f2bf(u.x); a[1] = (short)f2bf(u.y);
    a[2] = (short)f2bf(u.z); a[3] = (short)f2bf(u.w);
    a[4] = (short)f2bf(v.x); a[5] = (short)f2bf(v.y);
    a[6] = (short)f2bf(v.z); a[7] = (short)f2bf(v.w);
    const bf16x8 b = *(const bf16x8*)(bp + fi);
    acc = __builtin_amdgcn_mfma_f32_16x16x32_bf16(a, b, acc, 0, 0, 0);
  }

  // ---- k-quarter reduce via scratch; write p[s] ----
  if (kq == 0) {
    #pragma unroll
    for (int i = 0; i < 4; ++i) sc[hh][fg * 4 + i][fr] = acc[i];
  }
  __syncthreads();
  if (kq == 1) {
    float* ps = p + (long)s * 524288 + (row0 + fg * 4) * 32 + hh * 16 + fr;
    #pragma unroll
    for (int i = 0; i < 4; ++i)
      ps[(long)i * 32] = acc[i] + sc[hh][fg * 4 + i][fr];
  }
}

// ---------------- K2: h = sum_s p[s]+b1; em = relu(conv1d(h)+cb)@w2+b2 ----------
__global__ __launch_bounds__(256) void k2_conv(
    const float* __restrict__ p, const float* __restrict__ b1,
    const float* __restrict__ cw, const float* __restrict__ cb,
    const float* __restrict__ w2, const float* __restrict__ b2,
    float* __restrict__ em) {
  const int g = blockIdx.x * 256 + threadIdx.x;   // 0..131071
  const int row  = g >> 3;
  const int isub = g & 7;
  const int i0   = isub << 2;
  const int li   = row & (LSEQ - 1);

  const float4* p4 = (const float4*)p;
  const float4 bv = ((const float4*)b1)[isub];
  float4 z; z.x = z.y = z.z = z.w = 0.f;

  auto hrow = [&](int r) -> float4 {
    float4 a = p4[(long)r * 8 + isub];
    #pragma unroll
    for (int s = 1; s < SPLITK; ++s) {
      float4 v = p4[(long)s * 131072 + (long)r * 8 + isub];
      a.x += v.x; a.y += v.y; a.z += v.z; a.w += v.w;
    }
    a.x += bv.x; a.y += bv.y; a.z += bv.z; a.w += bv.w;
    return a;
  };

  float4 hm = (li > 0)        ? hrow(row - 1) : z;
  float4 hc = hrow(row);
  float4 hp = (li < LSEQ - 1) ? hrow(row + 1) : z;

  float s[16];
  #pragma unroll
  for (int o = 0; o < 16; ++o) {
    const float4* wpq = (const float4*)(cw + o * 96 + i0 * 3);
    const float4 wa = wpq[0], wb = wpq[1], wc = wpq[2];
    s[o] = hm.x * wa.x + hc.x * wa.y + hp.x * wa.z
         + hm.y * wa.w + hc.y * wb.x + hp.y * wb.y
         + hm.z * wb.z + hc.z * wb.w + hp.z * wc.x
         + hm.w * wc.y + hc.w * wc.z + hp.w * wc.w;
  }
  #pragma unroll
  for (int o = 0; o < 16; ++o) {
    s[o] += __shfl_xor(s[o], 1, 8);
    s[o] += __shfl_xor(s[o], 2, 8);
    s[o] += __shfl_xor(s[o], 4, 8);
  }
  if (isub == 0) {
    float e0 = b2[0], e1 = b2[1];
    #pragma unroll
    for (int o = 0; o < 16; ++o) {
      float rr = fmaxf(s[o] + cb[o], 0.f);
      e0 += rr * w2[o * 2];
      e1 += rr * w2[o * 2 + 1];
    }
    float2 ev; ev.x = e0; ev.y = e1;
    *(float2*)(em + (long)row * 2) = ev;
  }
}

// ---------------- K3: per-batch CRF, role-split (16 blocks) ----------------
__global__ __launch_bounds__(256) void k3_crf(
    const float* __restrict__ em, const int* __restrict__ tokens_length,
    const int* __restrict__ labels, const float* __restrict__ start_trans,
    const float* __restrict__ end_trans, const float* __restrict__ trans,
    float* __restrict__ llh, float* __restrict__ out) {
  __shared__ float sem[LSEQ * 2];
  __shared__ unsigned char hist[LSEQ];
  __shared__ float4 mats[256];
  __shared__ float red[256];
  __shared__ unsigned char bmA[256], bmB[256];
  __shared__ int s_last;

  const int t = threadIdx.x;
  const int b = blockIdx.x & 7;
  const int role = blockIdx.x >> 3;
  const int len = tokens_length[b];
  const float t00 = trans[0], t01 = trans[1], t10 = trans[2], t11 = trans[3];
  const float st0 = start_trans[0], st1 = start_trans[1];
  const float en0 = end_trans[0], en1 = end_trans[1];
  const int* lab = labels + b * LSEQ;

  {
    const float4* src4 = (const float4*)(em + (long)b * LSEQ * 2);
    float4* dst4 = (float4*)sem;
    #pragma unroll
    for (int i = t; i < LSEQ * 2 / 4; i += 256) dst4[i] = src4[i];
    if (role == 1) {
      #pragma unroll
      for (int l = t; l < LSEQ; l += 256) hist[l] = 2;
    }
  }
  __syncthreads();

  int lo = t * 8; if (lo < 1) lo = 1;
  int hi = t * 8 + 8; if (hi > len) hi = len;

  if (role == 0) {
    float sc = 0.f;
    {
      const int base = t * 8;
      #pragma unroll
      for (int k = 0; k < 8; ++k) {
        int l = base + k;
        if (l >= 1 && l < len) {
          int lp = lab[l - 1], lc = lab[l];
          sc += trans[lp * 2 + lc] + sem[2 * l + lc];
        }
      }
    }
    red[t] = sc;

    {
      float p00 = 0.f, p01 = -1e30f, p10 = -1e30f, p11 = 0.f;
      for (int l = lo; l < hi; ++l) {
        float e0 = sem[2 * l], e1 = sem[2 * l + 1];
        float n00 = lsef(p00 + t00, p01 + t10) + e0;
        float n01 = lsef(p00 + t01, p01 + t11) + e1;
        float n10 = lsef(p10 + t00, p11 + t10) + e0;
        float n11 = lsef(p10 + t01, p11 + t11) + e1;
        p00 = n00; p01 = n01; p10 = n10; p11 = n11;
      }
      float4 m; m.x = p00; m.y = p01; m.z = p10; m.w = p11; mats[t] = m;
    }
    __syncthreads();

    for (int n = 128; n >= 1; n >>= 1) {
      if (t < n) red[t] += red[t + n];
      __syncthreads();
    }
    for (int n = 128; n >= 1; n >>= 1) {
      float4 A, B; const bool act = (t < n);
      if (act) { A = mats[2 * t]; B = mats[2 * t + 1]; }
      __syncthreads();
      if (act) {
        float4 C;
        C.x = lsef(A.x + B.x, A.y + B.z);
        C.y = lsef(A.x + B.y, A.y + B.w);
        C.z = lsef(A.z + B.x, A.w + B.z);
        C.w = lsef(A.z + B.y, A.w + B.w);
        mats[t] = C;
      }
      __syncthreads();
    }

    if (t == 0) {
      int lab0 = lab[0];
      float s0 = (lab0 ? st1 : st0) + sem[lab0];
      int labe = lab[len - 1];
      float score = red[0] + s0 + (labe ? en1 : en0);
      float4 M = mats[0];
      float a00 = st0 + sem[0], a01 = st1 + sem[1];
      float af0 = lsef(a00 + M.x, a01 + M.z);
      float af1 = lsef(a00 + M.y, a01 + M.w);
      float norm = lsef(af0 + en0, af1 + en1);
      llh[b] = score - norm;
    }
    return;
  }

  // role 1: Viterbi forward max-plus chunk scan
  {
    float q00 = 0.f, q01 = -1e30f, q10 = -1e30f, q11 = 0.f;
    for (int l = lo; l < hi; ++l) {
      float e0 = sem[2 * l], e1 = sem[2 * l + 1];
      float n00 = fmaxf(q00 + t00, q01 + t10) + e0;
      float n01 = fmaxf(q00 + t01, q01 + t11) + e1;
      float n10 = fmaxf(q10 + t00, q11 + t10) + e0;
      float n11 = fmaxf(q10 + t01, q11 + t11) + e1;
      q00 = n00; q01 = n01; q10 = n10; q11 = n11;
    }
    float4 m; m.x = q00; m.y = q01; m.z = q10; m.w = q11; mats[t] = m;
  }
  __syncthreads();

  for (int off = 1; off < 256; off <<= 1) {
    float4 cur = mats[t];
    float4 prv;
    const bool has = (t >= off);
    if (has) prv = mats[t - off];
    __syncthreads();
    if (has) {
      float4 c;
      c.x = fmaxf(prv.x + cur.x, prv.y + cur.z);
      c.y = fmaxf(prv.x + cur.y, prv.y + cur.w);
      c.z = fmaxf(prv.z + cur.x, prv.w + cur.z);
      c.w = fmaxf(prv.z + cur.y, prv.w + cur.w);
      mats[t] = c;
    }
    __syncthreads();
  }

  {
    const float v00 = st0 + sem[0], v01 = st1 + sem[1];
    float vp0, vp1;
    if (t == 0) { vp0 = v00; vp1 = v01; }
    else {
      float4 E = mats[t - 1];
      vp0 = fmaxf(v00 + E.x, v01 + E.z);
      vp1 = fmaxf(v00 + E.y, v01 + E.w);
    }
    for (int l = lo; l < hi; ++l) {
      float e0 = sem[2 * l], e1 = sem[2 * l + 1];
      float s00 = vp0 + t00, s10 = vp1 + t10;
      float s01 = vp0 + t01, s11 = vp1 + t11;
      hist[l] = (unsigned char)((s00 >= s10 ? 0 : 1) | ((s01 >= s11 ? 0 : 1) << 1));
      vp0 = fmaxf(s00, s10) + e0;
      vp1 = fmaxf(s01, s11) + e1;
    }
    if (hi == len && lo < hi)
      s_last = (vp0 + en0 >= vp1 + en1) ? 0 : 1;
    if (t == 0 && len == 1)
      s_last = (v00 + en0 >= v01 + en1) ? 0 : 1;
  }
  __syncthreads();
  const int last = s_last;

  {
    int blo = (t == 0) ? 1 : t * 8;
    int bhi = t * 8 + 8;
    int m0 = 0, m1 = 1;
    for (int l = bhi - 1; l >= blo; --l) {
      int h = hist[l];
      m0 = (h >> m0) & 1;
      m1 = (h >> m1) & 1;
    }
    bmA[t] = (unsigned char)(m0 | (m1 << 1));
  }
  __syncthreads();
  {
    unsigned char* sarr = bmA; unsigned char* darr = bmB;
    for (int off = 1; off < 256; off <<= 1) {
      int a = sarr[t];
      int c = a;
      if (t + off < 256) {
        int bm = sarr[t + off];
        int c0 = (a >> (bm & 1)) & 1;
        int c1 = (a >> ((bm >> 1) & 1)) & 1;
        c = c0 | (c1 << 1);
      }
      darr[t] = (unsigned char)c;
      __syncthreads();
      unsigned char* tmp = sarr; sarr = darr; darr = tmp;
    }
    int xv = (t == 255) ? last : ((sarr[t + 1] >> last) & 1);
    int blo = (t == 0) ? 1 : t * 8;
    int bhi = t * 8 + 8;
    float* tout = out + 1 + b * LSEQ;
    for (int l = bhi - 1; l >= blo; --l) {
      xv = (hist[l] >> xv) & 1;
      int pidx = l - 1;
      tout[pidx] = (pidx < len) ? (float)xv : 0.0f;
    }
    if (t == 255) tout[LSEQ - 1] = ((LSEQ - 1) < len) ? (float)last : 0.0f;
  }
}

// ---------------- K4: deterministic final sum ----------------
__global__ void k4_final(const float* __restrict__ llh, float* __restrict__ out) {
  if (threadIdx.x == 0 && blockIdx.x == 0) {
    float s = 0.f;
    #pragma unroll
    for (int i = 0; i < NB; ++i) s += llh[i];
    out[0] = -s;
  }
}

extern "C" void kernel_launch(void* const* d_in, const int* in_sizes, int n_in,
                              void* d_out, int out_size, void* d_ws, size_t ws_size,
                              hipStream_t stream) {
  const float* x  = (const float*)d_in[0];
  const int*   tl = (const int*)d_in[1];
  const int*   lb = (const int*)d_in[2];
  const float* w1 = (const float*)d_in[3];
  const float* b1 = (const float*)d_in[4];
  const float* cw = (const float*)d_in[5];
  const float* cb = (const float*)d_in[6];
  const float* w2 = (const float*)d_in[7];
  const float* b2 = (const float*)d_in[8];
  const float* st = (const float*)d_in[9];
  const float* en = (const float*)d_in[10];
  const float* tr = (const float*)d_in[11];
  float* out = (float*)d_out;
  float* ws  = (float*)d_ws;

  float* p   = ws;                                   // 2 * 524288 floats (4 MB)
  float* em  = ws + (long)SPLITK * 524288;           // 32768 floats
  float* llh = em + 32768;                           // 8 floats
  unsigned short* w1T = (unsigned short*)(llh + 16); // 49152 ushorts (96 KB)

  hipLaunchKernelGGL(k0_wt, dim3(48), dim3(256), 0, stream, w1, w1T);
  hipLaunchKernelGGL(k1_mfma, dim3(1024 * SPLITK), dim3(256), 0, stream, x, w1T, p);
  hipLaunchKernelGGL(k2_conv, dim3(512), dim3(256), 0, stream, p, b1, cw, cb, w2, b2, em);
  hipLaunchKernelGGL(k3_crf, dim3(16), dim3(256), 0, stream, em, tl, lb, st, en, tr, llh, out);
  hipLaunchKernelGGL(k4_final, dim3(1), dim3(64), 0, stream, llh, out);
}

// Round 20
// 58.476 us; speedup vs baseline: 1.0571x; 1.0571x over previous
//
#include <hip/hip_runtime.h>

#define LSEQ 2048
#define DIN  1330
#define NB   8
#define SPLITK 7
#define KCH 192          // 6*32; 7*192 = 1344
#define K1PAD 1344
#define NSTEP 6

typedef short bf16x8 __attribute__((ext_vector_type(8)));
typedef float f32x4  __attribute__((ext_vector_type(4)));

__device__ __forceinline__ float lsef(float a, float b) {
  float m = fmaxf(a, b);
  float d = fminf(a, b) - m;
  return m + log1pf(__expf(d));
}

__device__ __forceinline__ unsigned short f2bf(float f) {   // RNE
  unsigned int u = __float_as_uint(f);
  return (unsigned short)((u + 0x7FFFu + ((u >> 16) & 1u)) >> 16);
}

// ordered 2x2 log-semiring product: A (earlier) then B (later)
__device__ __forceinline__ float4 lcomp(const float4 A, const float4 B) {
  float4 C;
  C.x = lsef(A.x + B.x, A.y + B.z);
  C.y = lsef(A.x + B.y, A.y + B.w);
  C.z = lsef(A.z + B.x, A.w + B.z);
  C.w = lsef(A.z + B.y, A.w + B.w);
  return C;
}
// ordered 2x2 max-plus product
__device__ __forceinline__ float4 mcomp(const float4 A, const float4 B) {
  float4 C;
  C.x = fmaxf(A.x + B.x, A.y + B.z);
  C.y = fmaxf(A.x + B.y, A.y + B.w);
  C.z = fmaxf(A.z + B.x, A.w + B.z);
  C.w = fmaxf(A.z + B.y, A.w + B.w);
  return C;
}
__device__ __forceinline__ float4 shfl_up4(const float4 v, int d) {
  float4 r;
  r.x = __shfl_up(v.x, d); r.y = __shfl_up(v.y, d);
  r.z = __shfl_up(v.z, d); r.w = __shfl_up(v.w, d);
  return r;
}
__device__ __forceinline__ float4 shfl_dn4(const float4 v, int d) {
  float4 r;
  r.x = __shfl_down(v.x, d); r.y = __shfl_down(v.y, d);
  r.z = __shfl_down(v.z, d); r.w = __shfl_down(v.w, d);
  return r;
}
// 2-bit map compose: apply B (later/inner) first, then A
__device__ __forceinline__ int bmcomp(int A, int B) {
  int c0 = (A >> (B & 1)) & 1;
  int c1 = (A >> ((B >> 1) & 1)) & 1;
  return c0 | (c1 << 1);
}

// ---------------- K0: w1 fp32 [k][h] -> w1T bf16 [h][K1PAD] (zero-padded) --------
__global__ __launch_bounds__(256) void k0_wt(
    const float* __restrict__ w1, unsigned short* __restrict__ w1T) {
  const int f = (blockIdx.x * 256 + threadIdx.x) * 4;   // 42 blocks * 1024 = 43008
  const int h = f / K1PAD, k = f % K1PAD;
  ushort4 v;
  v.x = (k     < DIN) ? f2bf(w1[(long)(k)     * 32 + h]) : (unsigned short)0;
  v.y = (k + 1 < DIN) ? f2bf(w1[(long)(k + 1) * 32 + h]) : (unsigned short)0;
  v.z = (k + 2 < DIN) ? f2bf(w1[(long)(k + 2) * 32 + h]) : (unsigned short)0;
  v.w = (k + 3 < DIN) ? f2bf(w1[(long)(k + 3) * 32 + h]) : (unsigned short)0;
  *(ushort4*)(w1T + f) = v;
}

// ---------------- K1: p[s] = x[:,ks] @ w1[ks,:] via MFMA, zero-LDS (r17) --------
__global__ __launch_bounds__(256) void k1_mfma(
    const float* __restrict__ x, const unsigned short* __restrict__ w1T,
    float* __restrict__ p) {
  const int tid  = threadIdx.x;
  const int rb   = blockIdx.x / SPLITK;
  const int s    = blockIdx.x % SPLITK;
  const int k0   = s * KCH;

  const int wv   = tid >> 6;
  const int lane = tid & 63;
  const int fr   = lane & 15;
  const int fg   = lane >> 4;

  const long row  = (long)rb * 64 + wv * 16 + fr;
  const float* ap = x + row * DIN;
  const unsigned short* bp0 = w1T + (long)fr * K1PAD;
  const unsigned short* bp1 = w1T + (long)(16 + fr) * K1PAD;

  f32x4 acc0 = {0.f, 0.f, 0.f, 0.f};
  f32x4 acc1 = {0.f, 0.f, 0.f, 0.f};

  #pragma unroll
  for (int t = 0; t < NSTEP; ++t) {
    const int ka = k0 + t * 32 + fg * 8;
    float4 u, v;
    if (ka + 7 < DIN) {
      u = *(const float4*)(ap + ka);
      v = *(const float4*)(ap + ka + 4);
    } else {
      u = make_float4(0.f, 0.f, 0.f, 0.f);
      v = make_float4(0.f, 0.f, 0.f, 0.f);
      if (ka     < DIN) u.x = ap[ka];
      if (ka + 1 < DIN) u.y = ap[ka + 1];
      if (ka + 2 < DIN) u.z = ap[ka + 2];
      if (ka + 3 < DIN) u.w = ap[ka + 3];
      if (ka + 4 < DIN) v.x = ap[ka + 4];
      if (ka + 5 < DIN) v.y = ap[ka + 5];
      if (ka + 6 < DIN) v.z = ap[ka + 6];
      if (ka + 7 < DIN) v.w = ap[ka + 7];
    }
    bf16x8 a;
    a[0] = (short)f2bf(u.x); a[1] = (short)f2bf(u.y);
    a[2] = (short)f2bf(u.z); a[3] = (short)f2bf(u.w);
    a[4] = (short)f2bf(v.x); a[5] = (short)f2bf(v.y);
    a[6] = (short)f2bf(v.z); a[7] = (short)f2bf(v.w);

    const bf16x8 b0 = *(const bf16x8*)(bp0 + ka);
    const bf16x8 b1 = *(const bf16x8*)(bp1 + ka);

    acc0 = __builtin_amdgcn_mfma_f32_16x16x32_bf16(a, b0, acc0, 0, 0, 0);
    acc1 = __builtin_amdgcn_mfma_f32_16x16x32_bf16(a, b1, acc1, 0, 0, 0);
  }

  float* ps = p + (long)s * 524288 + ((long)rb * 64 + wv * 16 + fg * 4) * 32;
  #pragma unroll
  for (int i = 0; i < 4; ++i) {
    ps[(long)i * 32 + fr]      = acc0[i];
    ps[(long)i * 32 + 16 + fr] = acc1[i];
  }
}

// ---------------- K2: h = sum_s p[s]+b1; em = relu(conv1d(h)+cb)@w2+b2 (r17) ----
__global__ __launch_bounds__(256) void k2_conv(
    const float* __restrict__ p, const float* __restrict__ b1,
    const float* __restrict__ cw, const float* __restrict__ cb,
    const float* __restrict__ w2, const float* __restrict__ b2,
    float* __restrict__ em) {
  const int g = blockIdx.x * 256 + threadIdx.x;
  const int row  = g >> 3;
  const int isub = g & 7;
  const int i0   = isub << 2;
  const int li   = row & (LSEQ - 1);

  const float4* p4 = (const float4*)p;
  const float4 bv = ((const float4*)b1)[isub];
  float4 z; z.x = z.y = z.z = z.w = 0.f;

  auto hrow = [&](int r) -> float4 {
    float4 a = p4[(long)r * 8 + isub];
    #pragma unroll
    for (int s = 1; s < SPLITK; ++s) {
      float4 v = p4[(long)s * 131072 + (long)r * 8 + isub];
      a.x += v.x; a.y += v.y; a.z += v.z; a.w += v.w;
    }
    a.x += bv.x; a.y += bv.y; a.z += bv.z; a.w += bv.w;
    return a;
  };

  float4 hm = (li > 0)        ? hrow(row - 1) : z;
  float4 hc = hrow(row);
  float4 hp = (li < LSEQ - 1) ? hrow(row + 1) : z;

  float s[16];
  #pragma unroll
  for (int o = 0; o < 16; ++o) {
    const float4* wpq = (const float4*)(cw + o * 96 + i0 * 3);
    const float4 wa = wpq[0], wb = wpq[1], wc = wpq[2];
    s[o] = hm.x * wa.x + hc.x * wa.y + hp.x * wa.z
         + hm.y * wa.w + hc.y * wb.x + hp.y * wb.y
         + hm.z * wb.z + hc.z * wb.w + hp.z * wc.x
         + hm.w * wc.y + hc.w * wc.z + hp.w * wc.w;
  }
  #pragma unroll
  for (int o = 0; o < 16; ++o) {
    s[o] += __shfl_xor(s[o], 1, 8);
    s[o] += __shfl_xor(s[o], 2, 8);
    s[o] += __shfl_xor(s[o], 4, 8);
  }
  if (isub == 0) {
    float e0 = b2[0], e1 = b2[1];
    #pragma unroll
    for (int o = 0; o < 16; ++o) {
      float rr = fmaxf(s[o] + cb[o], 0.f);
      e0 += rr * w2[o * 2];
      e1 += rr * w2[o * 2 + 1];
    }
    float2 ev; ev.x = e0; ev.y = e1;
    *(float2*)(em + (long)row * 2) = ev;
  }
}

// ---------------- K3: per-batch CRF, shfl-scan low-barrier version ----------------
// v2: all LDS ping-pong/tree scans replaced by wave-level shfl segmented-doubling
// scans (ordered non-commutative 2x2 products in registers) + one 4-entry LDS
// cross-wave combine. Barriers: role0 2, role1 3 (was ~35) -- k3 was barrier-
// latency-bound (16 blocks, every barrier ~300-400cyc on the critical path).
__global__ __launch_bounds__(256) void k3_crf(
    const float* __restrict__ em, const int* __restrict__ tokens_length,
    const int* __restrict__ labels, const float* __restrict__ start_trans,
    const float* __restrict__ end_trans, const float* __restrict__ trans,
    float* __restrict__ llh, float* __restrict__ out) {
  __shared__ float sem[LSEQ * 2];
  __shared__ unsigned char hist[LSEQ];
  __shared__ float4 wmat[4];
  __shared__ float wred[4];
  __shared__ int wbm[4];
  __shared__ int s_last;

  const int t = threadIdx.x;
  const int b = blockIdx.x & 7;
  const int role = blockIdx.x >> 3;
  const int len = tokens_length[b];
  const float t00 = trans[0], t01 = trans[1], t10 = trans[2], t11 = trans[3];
  const float st0 = start_trans[0], st1 = start_trans[1];
  const float en0 = end_trans[0], en1 = end_trans[1];
  const int* lab = labels + b * LSEQ;

  const int wv   = t >> 6;
  const int lane = t & 63;

  {
    const float4* src4 = (const float4*)(em + (long)b * LSEQ * 2);
    float4* dst4 = (float4*)sem;
    #pragma unroll
    for (int i = t; i < LSEQ * 2 / 4; i += 256) dst4[i] = src4[i];
  }
  __syncthreads();

  int lo = t * 8; if (lo < 1) lo = 1;
  int hi = t * 8 + 8; if (hi > len) hi = len;

  const float4 IDENT = make_float4(0.f, -1e30f, -1e30f, 0.f);

  if (role == 0) {
    // ---- gold-score partial + wave shfl reduce ----
    float sc = 0.f;
    {
      const int base = t * 8;
      #pragma unroll
      for (int k = 0; k < 8; ++k) {
        int l = base + k;
        if (l >= 1 && l < len) {
          int lp = lab[l - 1], lc = lab[l];
          sc += trans[lp * 2 + lc] + sem[2 * l + lc];
        }
      }
    }
    #pragma unroll
    for (int d = 1; d < 64; d <<= 1) sc += __shfl_down(sc, d);

    // ---- log-partition chunk product + ordered wave shfl reduce ----
    float4 M = IDENT;
    for (int l = lo; l < hi; ++l) {
      float e0 = sem[2 * l], e1 = sem[2 * l + 1];
      float4 S; S.x = t00 + e0; S.y = t01 + e1; S.z = t10 + e0; S.w = t11 + e1;
      M = lcomp(M, S);
    }
    #pragma unroll
    for (int d = 1; d < 64; d <<= 1) {
      float4 Mb = shfl_dn4(M, d);
      if (lane + d < 64) M = lcomp(M, Mb);
    }
    if (lane == 0) { wmat[wv] = M; wred[wv] = sc; }
    __syncthreads();

    if (t == 0) {
      float score_part = wred[0] + wred[1] + wred[2] + wred[3];
      float4 Mt = lcomp(lcomp(wmat[0], wmat[1]), lcomp(wmat[2], wmat[3]));
      int lab0 = lab[0];
      float s0 = (lab0 ? st1 : st0) + sem[lab0];
      int labe = lab[len - 1];
      float score = score_part + s0 + (labe ? en1 : en0);
      float a00 = st0 + sem[0], a01 = st1 + sem[1];
      float af0 = lsef(a00 + Mt.x, a01 + Mt.z);
      float af1 = lsef(a00 + Mt.y, a01 + Mt.w);
      float norm = lsef(af0 + en0, af1 + en1);
      llh[b] = score - norm;
    }
    return;
  }

  // ================= role 1: Viterbi =================
  // chunk max-plus product
  float4 M = IDENT;
  for (int l = lo; l < hi; ++l) {
    float e0 = sem[2 * l], e1 = sem[2 * l + 1];
    float4 S; S.x = t00 + e0; S.y = t01 + e1; S.z = t10 + e0; S.w = t11 + e1;
    M = mcomp(M, S);
  }
  // wave inclusive ordered scan
  #pragma unroll
  for (int d = 1; d < 64; d <<= 1) {
    float4 Mb = shfl_up4(M, d);
    if (lane >= d) M = mcomp(Mb, M);
  }
  float4 Mprev = shfl_up4(M, 1);          // inclusive of lane-1 (valid lane>0)
  if (lane == 63) wmat[wv] = M;           // wave total
  __syncthreads();

  // exclusive global prefix E for this thread
  float4 P = IDENT;
  for (int j = 0; j < wv; ++j) P = mcomp(P, wmat[j]);
  float4 E = (lane == 0) ? P : mcomp(P, Mprev);

  // decisions within chunk from vp (= v at chunk entry)
  {
    const float v00 = st0 + sem[0], v01 = st1 + sem[1];
    float vp0 = fmaxf(v00 + E.x, v01 + E.z);
    float vp1 = fmaxf(v00 + E.y, v01 + E.w);
    for (int l = lo; l < hi; ++l) {
      float e0 = sem[2 * l], e1 = sem[2 * l + 1];
      float s00 = vp0 + t00, s10 = vp1 + t10;
      float s01 = vp0 + t01, s11 = vp1 + t11;
      hist[l] = (unsigned char)((s00 >= s10 ? 0 : 1) | ((s01 >= s11 ? 0 : 1) << 1));
      vp0 = fmaxf(s00, s10) + e0;
      vp1 = fmaxf(s01, s11) + e1;
    }
    if (hi == len && lo < hi)
      s_last = (vp0 + en0 >= vp1 + en1) ? 0 : 1;
    if (t == 0 && len == 1)
      s_last = (v00 + en0 >= v01 + en1) ? 0 : 1;
  }

  // local backward map over own chunk (no cross-thread hist reads)
  int bm = 2;                              // identity map (0->0, 1->1)
  {
    int blo = (t == 0) ? 1 : t * 8;
    int bhi = t * 8 + 8;
    int m0 = 0, m1 = 1;
    for (int l = bhi - 1; l >= blo; --l) {
      int h = hist[l];
      m0 = (h >> m0) & 1;
      m1 = (h >> m1) & 1;
    }
    bm = m0 | (m1 << 1);
  }
  // wave suffix scan of maps (shfl, ordered: self outer, later inner)
  #pragma unroll
  for (int d = 1; d < 64; d <<= 1) {
    int bb = __shfl_down(bm, d);
    if (lane + d < 64) bm = bmcomp(bm, bb);
  }
  if (lane == 0) wbm[wv] = bm;            // whole-wave map
  __syncthreads();                         // also publishes s_last, hist

  int suf = 2;                             // suffix of later waves
  for (int j = 3; j > wv; --j) suf = bmcomp(wbm[j], suf);
  const int G = bmcomp(bm, suf);           // map over [t, 256) chunks
  int gn = __shfl_down(G, 1);
  if (lane == 63) gn = suf;                // next wave's start
  const int last = s_last;

  {
    int xv = (t == 255) ? last : ((gn >> last) & 1);
    int blo = (t == 0) ? 1 : t * 8;
    int bhi = t * 8 + 8;
    float* tout = out + 1 + b * LSEQ;
    for (int l = bhi - 1; l >= blo; --l) {
      xv = (hist[l] >> xv) & 1;
      int pidx = l - 1;
      tout[pidx] = (pidx < len) ? (float)xv : 0.0f;
    }
    if (t == 255) tout[LSEQ - 1] = ((LSEQ - 1) < len) ? (float)last : 0.0f;
  }
}

// ---------------- K4: deterministic final sum ----------------
__global__ void k4_final(const float* __restrict__ llh, float* __restrict__ out) {
  if (threadIdx.x == 0 && blockIdx.x == 0) {
    float s = 0.f;
    #pragma unroll
    for (int i = 0; i < NB; ++i) s += llh[i];
    out[0] = -s;
  }
}

extern "C" void kernel_launch(void* const* d_in, const int* in_sizes, int n_in,
                              void* d_out, int out_size, void* d_ws, size_t ws_size,
                              hipStream_t stream) {
  const float* x  = (const float*)d_in[0];
  const int*   tl = (const int*)d_in[1];
  const int*   lb = (const int*)d_in[2];
  const float* w1 = (const float*)d_in[3];
  const float* b1 = (const float*)d_in[4];
  const float* cw = (const float*)d_in[5];
  const float* cb = (const float*)d_in[6];
  const float* w2 = (const float*)d_in[7];
  const float* b2 = (const float*)d_in[8];
  const float* st = (const float*)d_in[9];
  const float* en = (const float*)d_in[10];
  const float* tr = (const float*)d_in[11];
  float* out = (float*)d_out;
  float* ws  = (float*)d_ws;

  float* p   = ws;                                   // 7 * 524288 floats (14 MB)
  float* em  = ws + (long)SPLITK * 524288;           // 32768 floats
  float* llh = em + 32768;                           // 8 floats
  unsigned short* w1T = (unsigned short*)(llh + 16); // 43008 ushorts (86 KB)

  hipLaunchKernelGGL(k0_wt, dim3(42), dim3(256), 0, stream, w1, w1T);
  hipLaunchKernelGGL(k1_mfma, dim3(256 * SPLITK), dim3(256), 0, stream, x, w1T, p);
  hipLaunchKernelGGL(k2_conv, dim3(512), dim3(256), 0, stream, p, b1, cw, cb, w2, b2, em);
  hipLaunchKernelGGL(k3_crf, dim3(16), dim3(256), 0, stream, em, tl, lb, st, en, tr, llh, out);
  hipLaunchKernelGGL(k4_final, dim3(1), dim3(64), 0, stream, llh, out);
}

// Round 21
// 58.247 us; speedup vs baseline: 1.0613x; 1.0039x over previous
//
#include <hip/hip_runtime.h>

#define LSEQ 2048
#define DIN  1330
#define NB   8
#define SPLITK 7
#define KCH 192          // 6*32; 7*192 = 1344
#define K1PAD 1344
#define NSTEP 6

typedef short bf16x8 __attribute__((ext_vector_type(8)));
typedef float f32x4  __attribute__((ext_vector_type(4)));

__device__ __forceinline__ float lsef(float a, float b) {
  float m = fmaxf(a, b);
  float d = fminf(a, b) - m;
  return m + log1pf(__expf(d));
}

__device__ __forceinline__ unsigned short f2bf(float f) {   // RNE
  unsigned int u = __float_as_uint(f);
  return (unsigned short)((u + 0x7FFFu + ((u >> 16) & 1u)) >> 16);
}

__device__ __forceinline__ float4 lcomp(const float4 A, const float4 B) {
  float4 C;
  C.x = lsef(A.x + B.x, A.y + B.z);
  C.y = lsef(A.x + B.y, A.y + B.w);
  C.z = lsef(A.z + B.x, A.w + B.z);
  C.w = lsef(A.z + B.y, A.w + B.w);
  return C;
}
__device__ __forceinline__ float4 mcomp(const float4 A, const float4 B) {
  float4 C;
  C.x = fmaxf(A.x + B.x, A.y + B.z);
  C.y = fmaxf(A.x + B.y, A.y + B.w);
  C.z = fmaxf(A.z + B.x, A.w + B.z);
  C.w = fmaxf(A.z + B.y, A.w + B.w);
  return C;
}
__device__ __forceinline__ float4 shfl_up4(const float4 v, int d) {
  float4 r;
  r.x = __shfl_up(v.x, d); r.y = __shfl_up(v.y, d);
  r.z = __shfl_up(v.z, d); r.w = __shfl_up(v.w, d);
  return r;
}
__device__ __forceinline__ float4 shfl_dn4(const float4 v, int d) {
  float4 r;
  r.x = __shfl_down(v.x, d); r.y = __shfl_down(v.y, d);
  r.z = __shfl_down(v.z, d); r.w = __shfl_down(v.w, d);
  return r;
}
__device__ __forceinline__ int bmcomp(int A, int B) {
  int c0 = (A >> (B & 1)) & 1;
  int c1 = (A >> ((B >> 1) & 1)) & 1;
  return c0 | (c1 << 1);
}

// ---------------- K0: w1 fp32 [k][h] -> w1T bf16 [h][K1PAD] (zero-padded) --------
__global__ __launch_bounds__(256) void k0_wt(
    const float* __restrict__ w1, unsigned short* __restrict__ w1T) {
  const int f = (blockIdx.x * 256 + threadIdx.x) * 4;   // 42 blocks * 1024 = 43008
  const int h = f / K1PAD, k = f % K1PAD;
  ushort4 v;
  v.x = (k     < DIN) ? f2bf(w1[(long)(k)     * 32 + h]) : (unsigned short)0;
  v.y = (k + 1 < DIN) ? f2bf(w1[(long)(k + 1) * 32 + h]) : (unsigned short)0;
  v.z = (k + 2 < DIN) ? f2bf(w1[(long)(k + 2) * 32 + h]) : (unsigned short)0;
  v.w = (k + 3 < DIN) ? f2bf(w1[(long)(k + 3) * 32 + h]) : (unsigned short)0;
  *(ushort4*)(w1T + f) = v;
}

// ---------------- K1: p[s] = x[:,ks] @ w1[ks,:] via MFMA, zero-LDS (r17) --------
__global__ __launch_bounds__(256) void k1_mfma(
    const float* __restrict__ x, const unsigned short* __restrict__ w1T,
    float* __restrict__ p) {
  const int tid  = threadIdx.x;
  const int rb   = blockIdx.x / SPLITK;
  const int s    = blockIdx.x % SPLITK;
  const int k0   = s * KCH;

  const int wv   = tid >> 6;
  const int lane = tid & 63;
  const int fr   = lane & 15;
  const int fg   = lane >> 4;

  const long row  = (long)rb * 64 + wv * 16 + fr;
  const float* ap = x + row * DIN;
  const unsigned short* bp0 = w1T + (long)fr * K1PAD;
  const unsigned short* bp1 = w1T + (long)(16 + fr) * K1PAD;

  f32x4 acc0 = {0.f, 0.f, 0.f, 0.f};
  f32x4 acc1 = {0.f, 0.f, 0.f, 0.f};

  #pragma unroll
  for (int t = 0; t < NSTEP; ++t) {
    const int ka = k0 + t * 32 + fg * 8;
    float4 u, v;
    if (ka + 7 < DIN) {
      u = *(const float4*)(ap + ka);
      v = *(const float4*)(ap + ka + 4);
    } else {
      u = make_float4(0.f, 0.f, 0.f, 0.f);
      v = make_float4(0.f, 0.f, 0.f, 0.f);
      if (ka     < DIN) u.x = ap[ka];
      if (ka + 1 < DIN) u.y = ap[ka + 1];
      if (ka + 2 < DIN) u.z = ap[ka + 2];
      if (ka + 3 < DIN) u.w = ap[ka + 3];
      if (ka + 4 < DIN) v.x = ap[ka + 4];
      if (ka + 5 < DIN) v.y = ap[ka + 5];
      if (ka + 6 < DIN) v.z = ap[ka + 6];
      if (ka + 7 < DIN) v.w = ap[ka + 7];
    }
    bf16x8 a;
    a[0] = (short)f2bf(u.x); a[1] = (short)f2bf(u.y);
    a[2] = (short)f2bf(u.z); a[3] = (short)f2bf(u.w);
    a[4] = (short)f2bf(v.x); a[5] = (short)f2bf(v.y);
    a[6] = (short)f2bf(v.z); a[7] = (short)f2bf(v.w);

    const bf16x8 b0 = *(const bf16x8*)(bp0 + ka);
    const bf16x8 b1 = *(const bf16x8*)(bp1 + ka);

    acc0 = __builtin_amdgcn_mfma_f32_16x16x32_bf16(a, b0, acc0, 0, 0, 0);
    acc1 = __builtin_amdgcn_mfma_f32_16x16x32_bf16(a, b1, acc1, 0, 0, 0);
  }

  float* ps = p + (long)s * 524288 + ((long)rb * 64 + wv * 16 + fg * 4) * 32;
  #pragma unroll
  for (int i = 0; i < 4; ++i) {
    ps[(long)i * 32 + fr]      = acc0[i];
    ps[(long)i * 32 + 16 + fr] = acc1[i];
  }
}

// ---------------- K2: h = sum_s p[s]+b1; em = relu(conv1d(h)+cb)@w2+b2 ----------
// Also zeroes the k3 arrival counter (runs before k3 every call).
__global__ __launch_bounds__(256) void k2_conv(
    const float* __restrict__ p, const float* __restrict__ b1,
    const float* __restrict__ cw, const float* __restrict__ cb,
    const float* __restrict__ w2, const float* __restrict__ b2,
    float* __restrict__ em, int* __restrict__ counter) {
  if (blockIdx.x == 0 && threadIdx.x == 0) *counter = 0;

  const int g = blockIdx.x * 256 + threadIdx.x;
  const int row  = g >> 3;
  const int isub = g & 7;
  const int i0   = isub << 2;
  const int li   = row & (LSEQ - 1);

  const float4* p4 = (const float4*)p;
  const float4 bv = ((const float4*)b1)[isub];
  float4 z; z.x = z.y = z.z = z.w = 0.f;

  auto hrow = [&](int r) -> float4 {
    float4 a = p4[(long)r * 8 + isub];
    #pragma unroll
    for (int s = 1; s < SPLITK; ++s) {
      float4 v = p4[(long)s * 131072 + (long)r * 8 + isub];
      a.x += v.x; a.y += v.y; a.z += v.z; a.w += v.w;
    }
    a.x += bv.x; a.y += bv.y; a.z += bv.z; a.w += bv.w;
    return a;
  };

  float4 hm = (li > 0)        ? hrow(row - 1) : z;
  float4 hc = hrow(row);
  float4 hp = (li < LSEQ - 1) ? hrow(row + 1) : z;

  float s[16];
  #pragma unroll
  for (int o = 0; o < 16; ++o) {
    const float4* wpq = (const float4*)(cw + o * 96 + i0 * 3);
    const float4 wa = wpq[0], wb = wpq[1], wc = wpq[2];
    s[o] = hm.x * wa.x + hc.x * wa.y + hp.x * wa.z
         + hm.y * wa.w + hc.y * wb.x + hp.y * wb.y
         + hm.z * wb.z + hc.z * wb.w + hp.z * wc.x
         + hm.w * wc.y + hc.w * wc.z + hp.w * wc.w;
  }
  #pragma unroll
  for (int o = 0; o < 16; ++o) {
    s[o] += __shfl_xor(s[o], 1, 8);
    s[o] += __shfl_xor(s[o], 2, 8);
    s[o] += __shfl_xor(s[o], 4, 8);
  }
  if (isub == 0) {
    float e0 = b2[0], e1 = b2[1];
    #pragma unroll
    for (int o = 0; o < 16; ++o) {
      float rr = fmaxf(s[o] + cb[o], 0.f);
      e0 += rr * w2[o * 2];
      e1 += rr * w2[o * 2 + 1];
    }
    float2 ev; ev.x = e0; ev.y = e1;
    *(float2*)(em + (long)row * 2) = ev;
  }
}

// ---------------- K3: per-batch CRF + fused final sum ----------------
// role 0 (blocks 0-7): score + logZ straight from global em (no LDS stage,
// 1 barrier), write llh[b], last-arrival block sums llh[0..7] IN ORDER
// (deterministic) -> out[0]. role 1 (blocks 8-15): Viterbi (r20 shfl version).
__global__ __launch_bounds__(256) void k3_crf(
    const float* __restrict__ em, const int* __restrict__ tokens_length,
    const int* __restrict__ labels, const float* __restrict__ start_trans,
    const float* __restrict__ end_trans, const float* __restrict__ trans,
    float* __restrict__ llh, int* __restrict__ counter,
    float* __restrict__ out) {
  __shared__ float sem[LSEQ * 2];
  __shared__ unsigned char hist[LSEQ];
  __shared__ float4 wmat[4];
  __shared__ float wred[4];
  __shared__ int wbm[4];
  __shared__ int s_last;

  const int t = threadIdx.x;
  const int b = blockIdx.x & 7;
  const int role = blockIdx.x >> 3;
  const int len = tokens_length[b];
  const float t00 = trans[0], t01 = trans[1], t10 = trans[2], t11 = trans[3];
  const float st0 = start_trans[0], st1 = start_trans[1];
  const float en0 = end_trans[0], en1 = end_trans[1];
  const int* lab = labels + b * LSEQ;

  const int wv   = t >> 6;
  const int lane = t & 63;

  int lo = t * 8; if (lo < 1) lo = 1;
  int hi = t * 8 + 8; if (hi > len) hi = len;

  const float4 IDENT = make_float4(0.f, -1e30f, -1e30f, 0.f);

  if (role == 0) {
    const float* ge = em + (long)b * LSEQ * 2;

    // gold-score partial (direct global reads) + wave shfl reduce
    float sc = 0.f;
    {
      const int base = t * 8;
      #pragma unroll
      for (int k = 0; k < 8; ++k) {
        int l = base + k;
        if (l >= 1 && l < len) {
          int lp = lab[l - 1], lc = lab[l];
          sc += trans[lp * 2 + lc] + ge[2 * l + lc];
        }
      }
    }
    #pragma unroll
    for (int d = 1; d < 64; d <<= 1) sc += __shfl_down(sc, d);

    // log-partition chunk product + ordered wave shfl reduce
    float4 M = IDENT;
    for (int l = lo; l < hi; ++l) {
      float2 e = *(const float2*)(ge + 2 * l);
      float4 S; S.x = t00 + e.x; S.y = t01 + e.y; S.z = t10 + e.x; S.w = t11 + e.y;
      M = lcomp(M, S);
    }
    #pragma unroll
    for (int d = 1; d < 64; d <<= 1) {
      float4 Mb = shfl_dn4(M, d);
      if (lane + d < 64) M = lcomp(M, Mb);
    }
    if (lane == 0) { wmat[wv] = M; wred[wv] = sc; }
    __syncthreads();

    if (t == 0) {
      float score_part = wred[0] + wred[1] + wred[2] + wred[3];
      float4 Mt = lcomp(lcomp(wmat[0], wmat[1]), lcomp(wmat[2], wmat[3]));
      int lab0 = lab[0];
      float s0 = (lab0 ? st1 : st0) + ge[lab0];
      int labe = lab[len - 1];
      float score = score_part + s0 + (labe ? en1 : en0);
      float a00 = st0 + ge[0], a01 = st1 + ge[1];
      float af0 = lsef(a00 + Mt.x, a01 + Mt.z);
      float af1 = lsef(a00 + Mt.y, a01 + Mt.w);
      float norm = lsef(af0 + en0, af1 + en1);
      llh[b] = score - norm;
      __threadfence();
      int old = atomicAdd(counter, 1);
      if (old == NB - 1) {                 // last role-0 block: fused k4
        __threadfence();
        const volatile float* lv = llh;
        float ssum = 0.f;
        #pragma unroll
        for (int i = 0; i < NB; ++i) ssum += lv[i];   // fixed order: deterministic
        out[0] = -ssum;
      }
    }
    return;
  }

  // ================= role 1: Viterbi (r20 shfl version) =================
  {
    const float4* src4 = (const float4*)(em + (long)b * LSEQ * 2);
    float4* dst4 = (float4*)sem;
    #pragma unroll
    for (int i = t; i < LSEQ * 2 / 4; i += 256) dst4[i] = src4[i];
    #pragma unroll
    for (int l = t; l < LSEQ; l += 256) hist[l] = 2;
  }
  __syncthreads();

  float4 M = IDENT;
  for (int l = lo; l < hi; ++l) {
    float e0 = sem[2 * l], e1 = sem[2 * l + 1];
    float4 S; S.x = t00 + e0; S.y = t01 + e1; S.z = t10 + e0; S.w = t11 + e1;
    M = mcomp(M, S);
  }
  #pragma unroll
  for (int d = 1; d < 64; d <<= 1) {
    float4 Mb = shfl_up4(M, d);
    if (lane >= d) M = mcomp(Mb, M);
  }
  float4 Mprev = shfl_up4(M, 1);
  if (lane == 63) wmat[wv] = M;
  __syncthreads();

  float4 P = IDENT;
  for (int j = 0; j < wv; ++j) P = mcomp(P, wmat[j]);
  float4 E = (lane == 0) ? P : mcomp(P, Mprev);

  {
    const float v00 = st0 + sem[0], v01 = st1 + sem[1];
    float vp0 = fmaxf(v00 + E.x, v01 + E.z);
    float vp1 = fmaxf(v00 + E.y, v01 + E.w);
    for (int l = lo; l < hi; ++l) {
      float e0 = sem[2 * l], e1 = sem[2 * l + 1];
      float s00 = vp0 + t00, s10 = vp1 + t10;
      float s01 = vp0 + t01, s11 = vp1 + t11;
      hist[l] = (unsigned char)((s00 >= s10 ? 0 : 1) | ((s01 >= s11 ? 0 : 1) << 1));
      vp0 = fmaxf(s00, s10) + e0;
      vp1 = fmaxf(s01, s11) + e1;
    }
    if (hi == len && lo < hi)
      s_last = (vp0 + en0 >= vp1 + en1) ? 0 : 1;
    if (t == 0 && len == 1)
      s_last = (v00 + en0 >= v01 + en1) ? 0 : 1;
  }

  int bm = 2;
  {
    int blo = (t == 0) ? 1 : t * 8;
    int bhi = t * 8 + 8;
    int m0 = 0, m1 = 1;
    for (int l = bhi - 1; l >= blo; --l) {
      int h = hist[l];
      m0 = (h >> m0) & 1;
      m1 = (h >> m1) & 1;
    }
    bm = m0 | (m1 << 1);
  }
  #pragma unroll
  for (int d = 1; d < 64; d <<= 1) {
    int bb = __shfl_down(bm, d);
    if (lane + d < 64) bm = bmcomp(bm, bb);
  }
  if (lane == 0) wbm[wv] = bm;
  __syncthreads();

  int suf = 2;
  for (int j = 3; j > wv; --j) suf = bmcomp(wbm[j], suf);
  const int G = bmcomp(bm, suf);
  int gn = __shfl_down(G, 1);
  if (lane == 63) gn = suf;
  const int last = s_last;

  {
    int xv = (t == 255) ? last : ((gn >> last) & 1);
    int blo = (t == 0) ? 1 : t * 8;
    int bhi = t * 8 + 8;
    float* tout = out + 1 + b * LSEQ;
    for (int l = bhi - 1; l >= blo; --l) {
      xv = (hist[l] >> xv) & 1;
      int pidx = l - 1;
      tout[pidx] = (pidx < len) ? (float)xv : 0.0f;
    }
    if (t == 255) tout[LSEQ - 1] = ((LSEQ - 1) < len) ? (float)last : 0.0f;
  }
}

extern "C" void kernel_launch(void* const* d_in, const int* in_sizes, int n_in,
                              void* d_out, int out_size, void* d_ws, size_t ws_size,
                              hipStream_t stream) {
  const float* x  = (const float*)d_in[0];
  const int*   tl = (const int*)d_in[1];
  const int*   lb = (const int*)d_in[2];
  const float* w1 = (const float*)d_in[3];
  const float* b1 = (const float*)d_in[4];
  const float* cw = (const float*)d_in[5];
  const float* cb = (const float*)d_in[6];
  const float* w2 = (const float*)d_in[7];
  const float* b2 = (const float*)d_in[8];
  const float* st = (const float*)d_in[9];
  const float* en = (const float*)d_in[10];
  const float* tr = (const float*)d_in[11];
  float* out = (float*)d_out;
  float* ws  = (float*)d_ws;

  float* p   = ws;                                   // 7 * 524288 floats (14 MB)
  float* em  = ws + (long)SPLITK * 524288;           // 32768 floats
  float* llh = em + 32768;                           // 8 floats
  int*  ctr  = (int*)(llh + 8);                      // 1 int (+pad)
  unsigned short* w1T = (unsigned short*)(llh + 16); // 43008 ushorts (86 KB)

  hipLaunchKernelGGL(k0_wt, dim3(42), dim3(256), 0, stream, w1, w1T);
  hipLaunchKernelGGL(k1_mfma, dim3(256 * SPLITK), dim3(256), 0, stream, x, w1T, p);
  hipLaunchKernelGGL(k2_conv, dim3(512), dim3(256), 0, stream, p, b1, cw, cb, w2, b2, em, ctr);
  hipLaunchKernelGGL(k3_crf, dim3(16), dim3(256), 0, stream, em, tl, lb, st, en, tr, llh, ctr, out);
}

// Round 22
// 58.026 us; speedup vs baseline: 1.0653x; 1.0038x over previous
//
#include <hip/hip_runtime.h>

#define LSEQ 2048
#define DIN  1330
#define NB   8
#define SPLITK 7
#define KCH 192          // 6*32; 7*192 = 1344
#define K1PAD 1344
#define NSTEP 6

typedef short bf16x8 __attribute__((ext_vector_type(8)));
typedef float f32x4  __attribute__((ext_vector_type(4)));

__device__ __forceinline__ float lsef(float a, float b) {
  float m = fmaxf(a, b);
  float d = fminf(a, b) - m;
  return m + log1pf(__expf(d));
}

__device__ __forceinline__ unsigned short f2bf(float f) {   // RNE
  unsigned int u = __float_as_uint(f);
  return (unsigned short)((u + 0x7FFFu + ((u >> 16) & 1u)) >> 16);
}

__device__ __forceinline__ float4 lcomp(const float4 A, const float4 B) {
  float4 C;
  C.x = lsef(A.x + B.x, A.y + B.z);
  C.y = lsef(A.x + B.y, A.y + B.w);
  C.z = lsef(A.z + B.x, A.w + B.z);
  C.w = lsef(A.z + B.y, A.w + B.w);
  return C;
}
__device__ __forceinline__ float4 mcomp(const float4 A, const float4 B) {
  float4 C;
  C.x = fmaxf(A.x + B.x, A.y + B.z);
  C.y = fmaxf(A.x + B.y, A.y + B.w);
  C.z = fmaxf(A.z + B.x, A.w + B.z);
  C.w = fmaxf(A.z + B.y, A.w + B.w);
  return C;
}
__device__ __forceinline__ float4 shfl_up4(const float4 v, int d) {
  float4 r;
  r.x = __shfl_up(v.x, d); r.y = __shfl_up(v.y, d);
  r.z = __shfl_up(v.z, d); r.w = __shfl_up(v.w, d);
  return r;
}
__device__ __forceinline__ float4 shfl_dn4(const float4 v, int d) {
  float4 r;
  r.x = __shfl_down(v.x, d); r.y = __shfl_down(v.y, d);
  r.z = __shfl_down(v.z, d); r.w = __shfl_down(v.w, d);
  return r;
}
__device__ __forceinline__ int bmcomp(int A, int B) {
  int c0 = (A >> (B & 1)) & 1;
  int c1 = (A >> ((B >> 1) & 1)) & 1;
  return c0 | (c1 << 1);
}

// ---------------- K0: w1 fp32 [k][h] -> w1T bf16 [h][K1PAD] (zero-padded) --------
__global__ __launch_bounds__(256) void k0_wt(
    const float* __restrict__ w1, unsigned short* __restrict__ w1T) {
  const int f = (blockIdx.x * 256 + threadIdx.x) * 4;   // 42 blocks * 1024 = 43008
  const int h = f / K1PAD, k = f % K1PAD;
  ushort4 v;
  v.x = (k     < DIN) ? f2bf(w1[(long)(k)     * 32 + h]) : (unsigned short)0;
  v.y = (k + 1 < DIN) ? f2bf(w1[(long)(k + 1) * 32 + h]) : (unsigned short)0;
  v.z = (k + 2 < DIN) ? f2bf(w1[(long)(k + 2) * 32 + h]) : (unsigned short)0;
  v.w = (k + 3 < DIN) ? f2bf(w1[(long)(k + 3) * 32 + h]) : (unsigned short)0;
  *(ushort4*)(w1T + f) = v;
}

// ---------------- K1: p[s] = x[:,ks] @ w1[ks,:] via MFMA, zero-LDS (r17) --------
__global__ __launch_bounds__(256) void k1_mfma(
    const float* __restrict__ x, const unsigned short* __restrict__ w1T,
    float* __restrict__ p) {
  const int tid  = threadIdx.x;
  const int rb   = blockIdx.x / SPLITK;
  const int s    = blockIdx.x % SPLITK;
  const int k0   = s * KCH;

  const int wv   = tid >> 6;
  const int lane = tid & 63;
  const int fr   = lane & 15;
  const int fg   = lane >> 4;

  const long row  = (long)rb * 64 + wv * 16 + fr;
  const float* ap = x + row * DIN;
  const unsigned short* bp0 = w1T + (long)fr * K1PAD;
  const unsigned short* bp1 = w1T + (long)(16 + fr) * K1PAD;

  f32x4 acc0 = {0.f, 0.f, 0.f, 0.f};
  f32x4 acc1 = {0.f, 0.f, 0.f, 0.f};

  #pragma unroll
  for (int t = 0; t < NSTEP; ++t) {
    const int ka = k0 + t * 32 + fg * 8;
    float4 u, v;
    if (ka + 7 < DIN) {
      u = *(const float4*)(ap + ka);
      v = *(const float4*)(ap + ka + 4);
    } else {
      u = make_float4(0.f, 0.f, 0.f, 0.f);
      v = make_float4(0.f, 0.f, 0.f, 0.f);
      if (ka     < DIN) u.x = ap[ka];
      if (ka + 1 < DIN) u.y = ap[ka + 1];
      if (ka + 2 < DIN) u.z = ap[ka + 2];
      if (ka + 3 < DIN) u.w = ap[ka + 3];
      if (ka + 4 < DIN) v.x = ap[ka + 4];
      if (ka + 5 < DIN) v.y = ap[ka + 5];
      if (ka + 6 < DIN) v.z = ap[ka + 6];
      if (ka + 7 < DIN) v.w = ap[ka + 7];
    }
    bf16x8 a;
    a[0] = (short)f2bf(u.x); a[1] = (short)f2bf(u.y);
    a[2] = (short)f2bf(u.z); a[3] = (short)f2bf(u.w);
    a[4] = (short)f2bf(v.x); a[5] = (short)f2bf(v.y);
    a[6] = (short)f2bf(v.z); a[7] = (short)f2bf(v.w);

    const bf16x8 b0 = *(const bf16x8*)(bp0 + ka);
    const bf16x8 b1 = *(const bf16x8*)(bp1 + ka);

    acc0 = __builtin_amdgcn_mfma_f32_16x16x32_bf16(a, b0, acc0, 0, 0, 0);
    acc1 = __builtin_amdgcn_mfma_f32_16x16x32_bf16(a, b1, acc1, 0, 0, 0);
  }

  float* ps = p + (long)s * 524288 + ((long)rb * 64 + wv * 16 + fg * 4) * 32;
  #pragma unroll
  for (int i = 0; i < 4; ++i) {
    ps[(long)i * 32 + fr]      = acc0[i];
    ps[(long)i * 32 + 16 + fr] = acc1[i];
  }
}

// ---------------- K2: h = sum_s p[s]+b1; em = relu(conv1d(h)+cb)@w2+b2 ----------
// v2: hc computed ONCE per row; hm/hp obtained via shfl (wave interior),
// LDS edge exchange (wave boundary), global fallback only for the 2 block-edge
// rows. Cuts p traffic ~3x (56 -> 20 MB). Values bit-identical (same hrow sum
// order, computed once). Batch (li) boundaries coincide with block boundaries
// (2048 %% 32 == 0) so li masks apply as before. Also zeroes k3's counter.
__global__ __launch_bounds__(256) void k2_conv(
    const float* __restrict__ p, const float* __restrict__ b1,
    const float* __restrict__ cw, const float* __restrict__ cb,
    const float* __restrict__ w2, const float* __restrict__ b2,
    float* __restrict__ em, int* __restrict__ counter) {
  __shared__ float4 edgeF[4][8];   // wave's first-row hc  [wave][isub]
  __shared__ float4 edgeL[4][8];   // wave's last-row  hc

  if (blockIdx.x == 0 && threadIdx.x == 0) *counter = 0;

  const int t    = threadIdx.x;
  const int g    = blockIdx.x * 256 + t;
  const int row  = g >> 3;
  const int isub = g & 7;
  const int i0   = isub << 2;
  const int li   = row & (LSEQ - 1);
  const int wv   = t >> 6;
  const int lane = t & 63;

  const float4* p4 = (const float4*)p;
  const float4 bv = ((const float4*)b1)[isub];
  float4 z; z.x = z.y = z.z = z.w = 0.f;

  auto hrow = [&](int r) -> float4 {
    float4 a = p4[(long)r * 8 + isub];
    #pragma unroll
    for (int s = 1; s < SPLITK; ++s) {
      float4 v = p4[(long)s * 131072 + (long)r * 8 + isub];
      a.x += v.x; a.y += v.y; a.z += v.z; a.w += v.w;
    }
    a.x += bv.x; a.y += bv.y; a.z += bv.z; a.w += bv.w;
    return a;
  };

  const float4 hc = hrow(row);

  // publish wave-edge rows
  if (lane < 8)   edgeF[wv][isub] = hc;
  if (lane >= 56) edgeL[wv][isub] = hc;
  __syncthreads();

  // neighbors via shfl within wave (wave = 8 rows)
  float4 hm = shfl_up4(hc, 8);
  float4 hp = shfl_dn4(hc, 8);
  if (lane < 8) {                       // first row of wave
    if (wv > 0) hm = edgeL[wv - 1][isub];
    else        hm = (li > 0) ? hrow(row - 1) : z;   // block edge
  }
  if (lane >= 56) {                     // last row of wave
    if (wv < 3) hp = edgeF[wv + 1][isub];
    else        hp = (li < LSEQ - 1) ? hrow(row + 1) : z;  // block edge
  }
  if (li == 0)        hm = z;           // batch boundary (block-aligned)
  if (li == LSEQ - 1) hp = z;

  float s[16];
  #pragma unroll
  for (int o = 0; o < 16; ++o) {
    const float4* wpq = (const float4*)(cw + o * 96 + i0 * 3);
    const float4 wa = wpq[0], wb = wpq[1], wc = wpq[2];
    s[o] = hm.x * wa.x + hc.x * wa.y + hp.x * wa.z
         + hm.y * wa.w + hc.y * wb.x + hp.y * wb.y
         + hm.z * wb.z + hc.z * wb.w + hp.z * wc.x
         + hm.w * wc.y + hc.w * wc.z + hp.w * wc.w;
  }
  #pragma unroll
  for (int o = 0; o < 16; ++o) {
    s[o] += __shfl_xor(s[o], 1, 8);
    s[o] += __shfl_xor(s[o], 2, 8);
    s[o] += __shfl_xor(s[o], 4, 8);
  }
  if (isub == 0) {
    float e0 = b2[0], e1 = b2[1];
    #pragma unroll
    for (int o = 0; o < 16; ++o) {
      float rr = fmaxf(s[o] + cb[o], 0.f);
      e0 += rr * w2[o * 2];
      e1 += rr * w2[o * 2 + 1];
    }
    float2 ev; ev.x = e0; ev.y = e1;
    *(float2*)(em + (long)row * 2) = ev;
  }
}

// ---------------- K3: per-batch CRF + fused final sum (r21) ----------------
__global__ __launch_bounds__(256) void k3_crf(
    const float* __restrict__ em, const int* __restrict__ tokens_length,
    const int* __restrict__ labels, const float* __restrict__ start_trans,
    const float* __restrict__ end_trans, const float* __restrict__ trans,
    float* __restrict__ llh, int* __restrict__ counter,
    float* __restrict__ out) {
  __shared__ float sem[LSEQ * 2];
  __shared__ unsigned char hist[LSEQ];
  __shared__ float4 wmat[4];
  __shared__ float wred[4];
  __shared__ int wbm[4];
  __shared__ int s_last;

  const int t = threadIdx.x;
  const int b = blockIdx.x & 7;
  const int role = blockIdx.x >> 3;
  const int len = tokens_length[b];
  const float t00 = trans[0], t01 = trans[1], t10 = trans[2], t11 = trans[3];
  const float st0 = start_trans[0], st1 = start_trans[1];
  const float en0 = end_trans[0], en1 = end_trans[1];
  const int* lab = labels + b * LSEQ;

  const int wv   = t >> 6;
  const int lane = t & 63;

  int lo = t * 8; if (lo < 1) lo = 1;
  int hi = t * 8 + 8; if (hi > len) hi = len;

  const float4 IDENT = make_float4(0.f, -1e30f, -1e30f, 0.f);

  if (role == 0) {
    const float* ge = em + (long)b * LSEQ * 2;

    float sc = 0.f;
    {
      const int base = t * 8;
      #pragma unroll
      for (int k = 0; k < 8; ++k) {
        int l = base + k;
        if (l >= 1 && l < len) {
          int lp = lab[l - 1], lc = lab[l];
          sc += trans[lp * 2 + lc] + ge[2 * l + lc];
        }
      }
    }
    #pragma unroll
    for (int d = 1; d < 64; d <<= 1) sc += __shfl_down(sc, d);

    float4 M = IDENT;
    for (int l = lo; l < hi; ++l) {
      float2 e = *(const float2*)(ge + 2 * l);
      float4 S; S.x = t00 + e.x; S.y = t01 + e.y; S.z = t10 + e.x; S.w = t11 + e.y;
      M = lcomp(M, S);
    }
    #pragma unroll
    for (int d = 1; d < 64; d <<= 1) {
      float4 Mb = shfl_dn4(M, d);
      if (lane + d < 64) M = lcomp(M, Mb);
    }
    if (lane == 0) { wmat[wv] = M; wred[wv] = sc; }
    __syncthreads();

    if (t == 0) {
      float score_part = wred[0] + wred[1] + wred[2] + wred[3];
      float4 Mt = lcomp(lcomp(wmat[0], wmat[1]), lcomp(wmat[2], wmat[3]));
      int lab0 = lab[0];
      float s0 = (lab0 ? st1 : st0) + ge[lab0];
      int labe = lab[len - 1];
      float score = score_part + s0 + (labe ? en1 : en0);
      float a00 = st0 + ge[0], a01 = st1 + ge[1];
      float af0 = lsef(a00 + Mt.x, a01 + Mt.z);
      float af1 = lsef(a00 + Mt.y, a01 + Mt.w);
      float norm = lsef(af0 + en0, af1 + en1);
      llh[b] = score - norm;
      __threadfence();
      int old = atomicAdd(counter, 1);
      if (old == NB - 1) {
        __threadfence();
        const volatile float* lv = llh;
        float ssum = 0.f;
        #pragma unroll
        for (int i = 0; i < NB; ++i) ssum += lv[i];
        out[0] = -ssum;
      }
    }
    return;
  }

  // role 1: Viterbi (shfl scan)
  {
    const float4* src4 = (const float4*)(em + (long)b * LSEQ * 2);
    float4* dst4 = (float4*)sem;
    #pragma unroll
    for (int i = t; i < LSEQ * 2 / 4; i += 256) dst4[i] = src4[i];
    #pragma unroll
    for (int l = t; l < LSEQ; l += 256) hist[l] = 2;
  }
  __syncthreads();

  float4 M = IDENT;
  for (int l = lo; l < hi; ++l) {
    float e0 = sem[2 * l], e1 = sem[2 * l + 1];
    float4 S; S.x = t00 + e0; S.y = t01 + e1; S.z = t10 + e0; S.w = t11 + e1;
    M = mcomp(M, S);
  }
  #pragma unroll
  for (int d = 1; d < 64; d <<= 1) {
    float4 Mb = shfl_up4(M, d);
    if (lane >= d) M = mcomp(Mb, M);
  }
  float4 Mprev = shfl_up4(M, 1);
  if (lane == 63) wmat[wv] = M;
  __syncthreads();

  float4 P = IDENT;
  for (int j = 0; j < wv; ++j) P = mcomp(P, wmat[j]);
  float4 E = (lane == 0) ? P : mcomp(P, Mprev);

  {
    const float v00 = st0 + sem[0], v01 = st1 + sem[1];
    float vp0 = fmaxf(v00 + E.x, v01 + E.z);
    float vp1 = fmaxf(v00 + E.y, v01 + E.w);
    for (int l = lo; l < hi; ++l) {
      float e0 = sem[2 * l], e1 = sem[2 * l + 1];
      float s00 = vp0 + t00, s10 = vp1 + t10;
      float s01 = vp0 + t01, s11 = vp1 + t11;
      hist[l] = (unsigned char)((s00 >= s10 ? 0 : 1) | ((s01 >= s11 ? 0 : 1) << 1));
      vp0 = fmaxf(s00, s10) + e0;
      vp1 = fmaxf(s01, s11) + e1;
    }
    if (hi == len && lo < hi)
      s_last = (vp0 + en0 >= vp1 + en1) ? 0 : 1;
    if (t == 0 && len == 1)
      s_last = (v00 + en0 >= v01 + en1) ? 0 : 1;
  }

  int bm = 2;
  {
    int blo = (t == 0) ? 1 : t * 8;
    int bhi = t * 8 + 8;
    int m0 = 0, m1 = 1;
    for (int l = bhi - 1; l >= blo; --l) {
      int h = hist[l];
      m0 = (h >> m0) & 1;
      m1 = (h >> m1) & 1;
    }
    bm = m0 | (m1 << 1);
  }
  #pragma unroll
  for (int d = 1; d < 64; d <<= 1) {
    int bb = __shfl_down(bm, d);
    if (lane + d < 64) bm = bmcomp(bm, bb);
  }
  if (lane == 0) wbm[wv] = bm;
  __syncthreads();

  int suf = 2;
  for (int j = 3; j > wv; --j) suf = bmcomp(wbm[j], suf);
  const int G = bmcomp(bm, suf);
  int gn = __shfl_down(G, 1);
  if (lane == 63) gn = suf;
  const int last = s_last;

  {
    int xv = (t == 255) ? last : ((gn >> last) & 1);
    int blo = (t == 0) ? 1 : t * 8;
    int bhi = t * 8 + 8;
    float* tout = out + 1 + b * LSEQ;
    for (int l = bhi - 1; l >= blo; --l) {
      xv = (hist[l] >> xv) & 1;
      int pidx = l - 1;
      tout[pidx] = (pidx < len) ? (float)xv : 0.0f;
    }
    if (t == 255) tout[LSEQ - 1] = ((LSEQ - 1) < len) ? (float)last : 0.0f;
  }
}

extern "C" void kernel_launch(void* const* d_in, const int* in_sizes, int n_in,
                              void* d_out, int out_size, void* d_ws, size_t ws_size,
                              hipStream_t stream) {
  const float* x  = (const float*)d_in[0];
  const int*   tl = (const int*)d_in[1];
  const int*   lb = (const int*)d_in[2];
  const float* w1 = (const float*)d_in[3];
  const float* b1 = (const float*)d_in[4];
  const float* cw = (const float*)d_in[5];
  const float* cb = (const float*)d_in[6];
  const float* w2 = (const float*)d_in[7];
  const float* b2 = (const float*)d_in[8];
  const float* st = (const float*)d_in[9];
  const float* en = (const float*)d_in[10];
  const float* tr = (const float*)d_in[11];
  float* out = (float*)d_out;
  float* ws  = (float*)d_ws;

  float* p   = ws;                                   // 7 * 524288 floats (14 MB)
  float* em  = ws + (long)SPLITK * 524288;           // 32768 floats
  float* llh = em + 32768;                           // 8 floats
  int*  ctr  = (int*)(llh + 8);                      // 1 int
  unsigned short* w1T = (unsigned short*)(llh + 16); // 43008 ushorts (86 KB)

  hipLaunchKernelGGL(k0_wt, dim3(42), dim3(256), 0, stream, w1, w1T);
  hipLaunchKernelGGL(k1_mfma, dim3(256 * SPLITK), dim3(256), 0, stream, x, w1T, p);
  hipLaunchKernelGGL(k2_conv, dim3(512), dim3(256), 0, stream, p, b1, cw, cb, w2, b2, em, ctr);
  hipLaunchKernelGGL(k3_crf, dim3(16), dim3(256), 0, stream, em, tl, lb, st, en, tr, llh, ctr, out);
}